// Round 10
// baseline (31.496 us; speedup 1.0000x reference)
//
#include <hip/hip_runtime.h>
#include <hip/hip_fp16.h>
#include <math.h>

// T=24, NSEQ=16384, FS=64, FM=16, FC=16 -> I=96; H=32.
//
// R10 = R3 structure + R8 math:
//  - ONE wave owns 16 seqs x ALL 96 gate rows: recurrence 100% in-register.
//    No LDS, no barriers, no cross-wave coupling. sigma k-permutation
//    (validated R3-R9): lane's 8 computed h' are exactly its own B-slots.
//  - f16 single-term h and x (validated R8/R9, absmax 0.0625), scaled by
//    log2e / 2log2e at pack time -> gates via exp2+rcp only.
//  - x-side xacc(t+1) (h-independent) computed during step t; parity-slot
//    2-step-deep x prefetch (no rotation).
//  - 1024 waves = 1/SIMD; per-step issue ~610cyc dominated by 48 trans ops;
//    8 independent per-unit gate chains keep the trans pipe fed.

typedef __attribute__((ext_vector_type(8))) short short8;
typedef __attribute__((ext_vector_type(8))) _Float16 half8;
typedef __attribute__((ext_vector_type(4))) float f32x4;

#define NSEQ 16384
#define TSTEPS 24
#define LOG2E 1.44269504088896340736f

// ws layout (ushort units)
#define P_HH   0        // [96][32] f16, scaled, sigma-k
#define P_MC   3072     // [96][32] f16, scaled, natural k (met|ctx)
#define P_SP   6144     // [96][64] f16, scaled (spatial)
#define P_WP_H 12288    // [64][32] f16 hi, Wp^T sigma-k
#define P_WP_L 14336    // [64][32] f16 lo
#define P_BIAS 16384    // 128 f32: [96] acc-bias scaled, [32] bhn scaled

__device__ __forceinline__ int sigma_inv(int ks) {
  int cc = ks >> 3, e = ks & 7;
  return (e < 4) ? (4 * cc + e) : (16 + 4 * cc + (e - 4));
}

__global__ void pack_w(const float* __restrict__ W_ih,
                       const float* __restrict__ W_hh,
                       const float* __restrict__ b_ih,
                       const float* __restrict__ b_hh,
                       const float* __restrict__ Wp,
                       unsigned short* __restrict__ ws) {
  int idx = blockIdx.x * blockDim.x + threadIdx.x;
  for (int i = idx; i < 14464; i += gridDim.x * blockDim.x) {
    if (i < 3072) {                       // W_hh f16, scaled, sigma-k
      int row = i >> 5, ks = i & 31;
      float sc = (row < 64) ? LOG2E : (2.0f * LOG2E);
      float v = W_hh[row * 32 + sigma_inv(ks)] * sc;
      ws[P_HH + i] = __half_as_ushort(__float2half(v));
    } else if (i < 6144) {                // W_ih cols 64..95 -> f16 scaled
      int j = i - 3072;
      int row = j >> 5, k = j & 31;
      float sc = (row < 64) ? LOG2E : (2.0f * LOG2E);
      ws[P_MC + j] = __half_as_ushort(__float2half(W_ih[row * 96 + 64 + k] * sc));
    } else if (i < 12288) {               // W_ih cols 0..63 -> f16 scaled
      int j = i - 6144;
      int row = j >> 6, k = j & 63;
      float sc = (row < 64) ? LOG2E : (2.0f * LOG2E);
      ws[P_SP + j] = __half_as_ushort(__float2half(W_ih[row * 96 + k] * sc));
    } else if (i < 14336) {               // Wp^T f16 hi/lo, sigma-k
      int j = i - 12288;
      int frow = j >> 5, ks = j & 31;
      float v = Wp[sigma_inv(ks) * 64 + frow];
      __half h = __float2half(v);
      float lo = v - __half2float(h);
      ws[P_WP_H + j] = __half_as_ushort(h);
      ws[P_WP_L + j] = __half_as_ushort(__float2half(lo));
    } else {                              // f32 bias blob
      int k = i - 14336;
      float* bb = (float*)(ws + P_BIAS);
      if (k < 96) {
        float sc = (k < 64) ? LOG2E : (2.0f * LOG2E);
        bb[k] = (b_ih[k] + (k < 64 ? b_hh[k] : 0.0f)) * sc;
      } else {
        bb[k] = 2.0f * LOG2E * b_hh[64 + (k - 96)];
      }
    }
  }
}

__device__ __forceinline__ float exp2_fast(float x) {
#if __has_builtin(__builtin_amdgcn_exp2f)
  return __builtin_amdgcn_exp2f(x);
#else
  return __expf(x * 0.6931471805599453f);
#endif
}

__device__ __forceinline__ unsigned int pk_f16(float a, float b) {
#if __has_builtin(__builtin_amdgcn_cvt_pkrtz)
  auto r = __builtin_amdgcn_cvt_pkrtz(a, b);   // __fp16 ext_vector(2)
  return __builtin_bit_cast(unsigned int, r);
#else
  return (unsigned)__half_as_ushort(__float2half(a)) |
         ((unsigned)__half_as_ushort(__float2half(b)) << 16);
#endif
}

__device__ __forceinline__ f32x4 mfma_h(half8 a, half8 b, f32x4 c) {
  return __builtin_amdgcn_mfma_f32_16x16x32_f16(a, b, c, 0, 0, 0);
}

union S8u { short8 v; unsigned int u[4]; };
union H8u { half8 v; unsigned int u[4]; };

__global__ __launch_bounds__(256)
void gru6(const float* __restrict__ spatial,
          const float* __restrict__ met,
          const float* __restrict__ ctx,
          const unsigned short* __restrict__ ws,
          float* __restrict__ out) {
  const int tid = threadIdx.x;
  const int lane = tid & 63;
  const int wv = tid >> 6;       // 4 independent waves per block
  const int l15 = lane & 15;
  const int c = lane >> 4;       // 0..3
  const int seq = blockIdx.x * 64 + wv * 16 + l15;
  const float* bb = (const float*)(ws + P_BIAS);
  const f32x4 zero4 = {0.f, 0.f, 0.f, 0.f};

  // ---- persistent weights: all 6 row tiles, f16 ----
  half8 whh[6], wmc[6];
#pragma unroll
  for (int j = 0; j < 6; ++j) {
    int off = (j * 16 + l15) * 32 + c * 8;
    S8u t0; t0.v = *(const short8*)(ws + P_HH + off);
    H8u h0; h0.u[0]=t0.u[0]; h0.u[1]=t0.u[1]; h0.u[2]=t0.u[2]; h0.u[3]=t0.u[3];
    whh[j] = h0.v;
    S8u t1; t1.v = *(const short8*)(ws + P_MC + off);
    H8u h1; h1.u[0]=t1.u[0]; h1.u[1]=t1.u[1]; h1.u[2]=t1.u[2]; h1.u[3]=t1.u[3];
    wmc[j] = h1.v;
  }

  // ---- bias init via f32 blob ----
  f32x4 acc_i[6], bhnA, bhnB;
#pragma unroll
  for (int j = 0; j < 6; ++j) {
    float4 v = *(const float4*)(bb + j * 16 + 4 * c);
    acc_i[j][0] = v.x; acc_i[j][1] = v.y; acc_i[j][2] = v.z; acc_i[j][3] = v.w;
  }
  {
    float4 va = *(const float4*)(bb + 96 + 4 * c);
    float4 vb = *(const float4*)(bb + 96 + 16 + 4 * c);
    bhnA[0] = va.x; bhnA[1] = va.y; bhnA[2] = va.z; bhnA[3] = va.w;
    bhnB[0] = vb.x; bhnB[1] = vb.y; bhnB[2] = vb.z; bhnB[3] = vb.w;
  }

  // ---- fold spatial (time-invariant) into acc_i ----
#pragma unroll
  for (int kt = 0; kt < 2; ++kt) {
    const float* sp = spatial + (size_t)seq * 64 + kt * 32 + c * 8;
    float4 a0 = *(const float4*)sp;
    float4 a1 = *(const float4*)(sp + 4);
    H8u sf;
    sf.u[0] = pk_f16(a0.x, a0.y); sf.u[1] = pk_f16(a0.z, a0.w);
    sf.u[2] = pk_f16(a1.x, a1.y); sf.u[3] = pk_f16(a1.z, a1.w);
#pragma unroll
    for (int j = 0; j < 6; ++j) {
      int row = j * 16 + l15;
      S8u t; t.v = *(const short8*)(ws + P_SP + row * 64 + kt * 32 + c * 8);
      H8u w2; w2.u[0]=t.u[0]; w2.u[1]=t.u[1]; w2.u[2]=t.u[2]; w2.u[3]=t.u[3];
      acc_i[j] = mfma_h(w2.v, sf.v, acc_i[j]);
    }
  }

  // ---- x: per-lane loads; parity-slot 2-deep prefetch ----
  const float* lptr = ((c < 2) ? met : ctx) + (size_t)seq * 16 + (c & 1) * 8;

  // xacc(0) = bias + spatial + Wmc*x(0)
  f32x4 xacc[6];
  {
    float4 a0 = *(const float4*)lptr;
    float4 a1 = *(const float4*)(lptr + 4);
    H8u xf;
    xf.u[0] = pk_f16(a0.x, a0.y); xf.u[1] = pk_f16(a0.z, a0.w);
    xf.u[2] = pk_f16(a1.x, a1.y); xf.u[3] = pk_f16(a1.z, a1.w);
#pragma unroll
    for (int j = 0; j < 6; ++j) xacc[j] = mfma_h(wmc[j], xf.v, acc_i[j]);
  }
  // slot s holds x(t+1) for the step t with t&1==s
  float4 xs0a = *(const float4*)(lptr + (size_t)1 * NSEQ * 16);
  float4 xs0b = *(const float4*)(lptr + (size_t)1 * NSEQ * 16 + 4);
  float4 xs1a = *(const float4*)(lptr + (size_t)2 * NSEQ * 16);
  float4 xs1b = *(const float4*)(lptr + (size_t)2 * NSEQ * 16 + 4);

  float hst[8];
#pragma unroll
  for (int i = 0; i < 8; ++i) hst[i] = 0.0f;
  H8u fh;
#pragma unroll
  for (int i = 0; i < 4; ++i) fh.u[i] = 0u;

#pragma unroll 2
  for (int t = 0; t < TSTEPS; ++t) {
    // save n-gate input parts before xacc is recomputed
    f32x4 ti0 = xacc[4], ti1 = xacc[5];

    // h-side: 6 independent f16 MFMAs (C = ready input-part accumulators)
    f32x4 dr0 = mfma_h(whh[0], fh.v, xacc[0]);
    f32x4 dr1 = mfma_h(whh[1], fh.v, xacc[1]);
    f32x4 dz0 = mfma_h(whh[2], fh.v, xacc[2]);
    f32x4 dz1 = mfma_h(whh[3], fh.v, xacc[3]);
    f32x4 th0 = mfma_h(whh[4], fh.v, bhnA);
    f32x4 th1 = mfma_h(whh[5], fh.v, bhnB);

    // x-side for t+1 (h-independent): consume parity slot, refill with x(t+3)
    {
      float4 xa = (t & 1) ? xs1a : xs0a;
      float4 xb = (t & 1) ? xs1b : xs0b;
      H8u xf;
      xf.u[0] = pk_f16(xa.x, xa.y); xf.u[1] = pk_f16(xa.z, xa.w);
      xf.u[2] = pk_f16(xb.x, xb.y); xf.u[3] = pk_f16(xb.z, xb.w);
#pragma unroll
      for (int j = 0; j < 6; ++j) xacc[j] = mfma_h(wmc[j], xf.v, acc_i[j]);
      int tf = (t + 3 < TSTEPS) ? (t + 3) : (TSTEPS - 1);
      float4 na = *(const float4*)(lptr + (size_t)tf * NSEQ * 16);
      float4 nb = *(const float4*)(lptr + (size_t)tf * NSEQ * 16 + 4);
      if (t & 1) { xs1a = na; xs1b = nb; } else { xs0a = na; xs0b = nb; }
    }

    // gates: 8 independent unit-chains (jj*4+q)
    float hv_[8];
#pragma unroll
    for (int jj = 0; jj < 2; ++jj) {
      f32x4 ddr = jj ? dr1 : dr0;
      f32x4 ddz = jj ? dz1 : dz0;
      f32x4 tth = jj ? th1 : th0;
      f32x4 tti = jj ? ti1 : ti0;
#pragma unroll
      for (int q = 0; q < 4; ++q) {
        int i = jj * 4 + q;
        float r = __builtin_amdgcn_rcpf(1.0f + exp2_fast(-ddr[q]));
        float z = __builtin_amdgcn_rcpf(1.0f + exp2_fast(-ddz[q]));
        float Y = fmaf(r, tth[q], tti[q]);
        float e = exp2_fast(-Y);
        float nn = fmaf(2.0f, __builtin_amdgcn_rcpf(1.0f + e), -1.0f);
        float hv = fmaf(z, hst[i] - nn, nn);
        hst[i] = hv;
        hv_[i] = hv;
      }
    }
    fh.u[0] = pk_f16(hv_[0], hv_[1]);
    fh.u[1] = pk_f16(hv_[2], hv_[3]);
    fh.u[2] = pk_f16(hv_[4], hv_[5]);
    fh.u[3] = pk_f16(hv_[6], hv_[7]);
  }

  // ---- projection: all 4 f-tiles, f16 2-term ----
#pragma unroll
  for (int pt = 0; pt < 4; ++pt) {
    int off = (pt * 16 + l15) * 32 + c * 8;
    S8u t0; t0.v = *(const short8*)(ws + P_WP_H + off);
    H8u wph; wph.u[0]=t0.u[0]; wph.u[1]=t0.u[1]; wph.u[2]=t0.u[2]; wph.u[3]=t0.u[3];
    S8u t1; t1.v = *(const short8*)(ws + P_WP_L + off);
    H8u wpl; wpl.u[0]=t1.u[0]; wpl.u[1]=t1.u[1]; wpl.u[2]=t1.u[2]; wpl.u[3]=t1.u[3];
    f32x4 o = mfma_h(wph.v, fh.v, zero4);
    o = mfma_h(wpl.v, fh.v, o);
    float* op = out + (size_t)seq * 64 + pt * 16 + 4 * c;
    *(float4*)op = make_float4(o[0], o[1], o[2], o[3]);
  }
}

extern "C" void kernel_launch(void* const* d_in, const int* in_sizes, int n_in,
                              void* d_out, int out_size, void* d_ws, size_t ws_size,
                              hipStream_t stream) {
  const float* spatial = (const float*)d_in[0];
  const float* met     = (const float*)d_in[1];
  const float* ctx     = (const float*)d_in[2];
  const float* W_ih    = (const float*)d_in[3];
  const float* W_hh    = (const float*)d_in[4];
  const float* b_ih    = (const float*)d_in[5];
  const float* b_hh    = (const float*)d_in[6];
  const float* Wp      = (const float*)d_in[7];
  float* out = (float*)d_out;
  unsigned short* ws = (unsigned short*)d_ws;

  hipLaunchKernelGGL(pack_w, dim3(57), dim3(256), 0, stream,
                     W_ih, W_hh, b_ih, b_hh, Wp, ws);
  hipLaunchKernelGGL(gru6, dim3(256), dim3(256), 0, stream,
                     spatial, met, ctx, ws, out);
}

// Round 11
// 26.250 us; speedup vs baseline: 1.1998x; 1.1998x over previous
//
#include <hip/hip_runtime.h>
#include <hip/hip_fp16.h>
#include <math.h>

// T=24, NSEQ=16384, FS=64, FM=16, FC=16 -> I=96; H=32.
//
// R11 = R9 (producer/consumer, 4 waves/block, 16 seqs/block, 1024 blocks,
// 4 waves/SIMD) with codegen fixes:
//  - NO unions: all fragment reinterpretation via __builtin_bit_cast of
//    ext_vector types (register-guaranteed; unions risk scratch).
//  - merged-rcp gates: h' = [h(1+e) + E(1-e)] / [(1+E)(1+e)]
//    (5 trans/unit instead of 6; E,e clamped to 1e30 -> inf-safe).
//  - s_setprio(1) on consumer waves (T5: needs role-split, which
//    producer/consumer provides).
// Structure (validated R9): consumers (waves 0,1) do the serial recurrence
// (3 f16 h-MFMAs + gates + uint2 h-exchange via sigma layout); producers
// (waves 2,3) compute xacc(t+1)=bias+spatial+Wmc*x(t+1) into double-buffered
// LDS tiles; one lgkm-only barrier/step.

typedef __attribute__((ext_vector_type(8))) short short8;
typedef __attribute__((ext_vector_type(8))) _Float16 half8;
typedef __attribute__((ext_vector_type(4))) float f32x4;
typedef __attribute__((ext_vector_type(4))) unsigned int uix4;

#define NSEQ 16384
#define TSTEPS 24
#define LOG2E 1.44269504088896340736f

// ws layout (ushort units)
#define P_HH   0        // [96][32] f16, scaled, sigma-k
#define P_MC   3072     // [96][32] f16, scaled, natural k (met|ctx)
#define P_SP   6144     // [96][64] f16, scaled (spatial)
#define P_WP_H 12288    // [64][32] f16 hi, Wp^T sigma-k
#define P_WP_L 14336    // [64][32] f16 lo
#define P_BIAS 16384    // 128 f32: [96] acc-bias scaled, [32] bhn scaled

__device__ __forceinline__ int sigma_inv(int ks) {
  int cc = ks >> 3, e = ks & 7;
  return (e < 4) ? (4 * cc + e) : (16 + 4 * cc + (e - 4));
}

__global__ void pack_w(const float* __restrict__ W_ih,
                       const float* __restrict__ W_hh,
                       const float* __restrict__ b_ih,
                       const float* __restrict__ b_hh,
                       const float* __restrict__ Wp,
                       unsigned short* __restrict__ ws) {
  int idx = blockIdx.x * blockDim.x + threadIdx.x;
  for (int i = idx; i < 14464; i += gridDim.x * blockDim.x) {
    if (i < 3072) {                       // W_hh f16, scaled, sigma-k
      int row = i >> 5, ks = i & 31;
      float sc = (row < 64) ? LOG2E : (2.0f * LOG2E);
      float v = W_hh[row * 32 + sigma_inv(ks)] * sc;
      ws[P_HH + i] = __half_as_ushort(__float2half(v));
    } else if (i < 6144) {                // W_ih cols 64..95 -> f16 scaled
      int j = i - 3072;
      int row = j >> 5, k = j & 31;
      float sc = (row < 64) ? LOG2E : (2.0f * LOG2E);
      ws[P_MC + j] = __half_as_ushort(__float2half(W_ih[row * 96 + 64 + k] * sc));
    } else if (i < 12288) {               // W_ih cols 0..63 -> f16 scaled
      int j = i - 6144;
      int row = j >> 6, k = j & 63;
      float sc = (row < 64) ? LOG2E : (2.0f * LOG2E);
      ws[P_SP + j] = __half_as_ushort(__float2half(W_ih[row * 96 + k] * sc));
    } else if (i < 14336) {               // Wp^T f16 hi/lo, sigma-k
      int j = i - 12288;
      int frow = j >> 5, ks = j & 31;
      float v = Wp[sigma_inv(ks) * 64 + frow];
      __half h = __float2half(v);
      float lo = v - __half2float(h);
      ws[P_WP_H + j] = __half_as_ushort(h);
      ws[P_WP_L + j] = __half_as_ushort(__float2half(lo));
    } else {                              // f32 bias blob
      int k = i - 14336;
      float* bb = (float*)(ws + P_BIAS);
      if (k < 96) {
        float sc = (k < 64) ? LOG2E : (2.0f * LOG2E);
        bb[k] = (b_ih[k] + (k < 64 ? b_hh[k] : 0.0f)) * sc;
      } else {
        bb[k] = 2.0f * LOG2E * b_hh[64 + (k - 96)];
      }
    }
  }
}

__device__ __forceinline__ float exp2_fast(float x) {
#if __has_builtin(__builtin_amdgcn_exp2f)
  return __builtin_amdgcn_exp2f(x);
#else
  return __expf(x * 0.6931471805599453f);
#endif
}

__device__ __forceinline__ unsigned int pk_f16(float a, float b) {
#if __has_builtin(__builtin_amdgcn_cvt_pkrtz)
  auto r = __builtin_amdgcn_cvt_pkrtz(a, b);   // __fp16 ext_vector(2)
  return __builtin_bit_cast(unsigned int, r);
#else
  return (unsigned)__half_as_ushort(__float2half(a)) |
         ((unsigned)__half_as_ushort(__float2half(b)) << 16);
#endif
}

// register-guaranteed reinterpret helpers (no unions)
__device__ __forceinline__ half8 ld_h8(const unsigned short* p) {
  return __builtin_bit_cast(half8, *(const short8*)p);
}
__device__ __forceinline__ half8 mk_h8(unsigned int a, unsigned int b,
                                       unsigned int c, unsigned int d) {
  uix4 v = {a, b, c, d};
  return __builtin_bit_cast(half8, v);
}

__device__ __forceinline__ f32x4 mfma_h(half8 a, half8 b, f32x4 c) {
  return __builtin_amdgcn_mfma_f32_16x16x32_f16(a, b, c, 0, 0, 0);
}

// workgroup barrier draining LDS ops only — global prefetch stays in flight
__device__ __forceinline__ void barrier_lds() {
  asm volatile("s_waitcnt lgkmcnt(0)" ::: "memory");
  __builtin_amdgcn_s_barrier();
}

__global__ __launch_bounds__(256, 4)
void gru7(const float* __restrict__ spatial,
          const float* __restrict__ met,
          const float* __restrict__ ctx,
          const unsigned short* __restrict__ ws,
          float* __restrict__ out) {
  // xacc tiles: [buf][tile(gate*2+half)][seq 16][20-pad f32]
  __shared__ float xls[2][6][16][20];
  __shared__ unsigned int hbuf[2][2][64][2];

  const int tid = threadIdx.x;
  const int lane = tid & 63;
  const int wv = tid >> 6;       // 0,1 consumer; 2,3 producer
  const int l15 = lane & 15;
  const int c = lane >> 4;       // 0..3
  const int seq = blockIdx.x * 16 + l15;
  const float* bb = (const float*)(ws + P_BIAS);
  const f32x4 zero4 = {0.f, 0.f, 0.f, 0.f};

  // zero initial-h buffer (hbuf[1] = 256 dwords; one per thread)
  ((unsigned int*)hbuf[1])[tid] = 0u;

  if (wv >= 2) {
    // ======================= PRODUCER =======================
    const int q = wv - 2;            // unit-half
    half8 wmc[3];
    f32x4 acc_i[3];
#pragma unroll
    for (int g = 0; g < 3; ++g) {
      int off = (g * 32 + q * 16 + l15) * 32 + c * 8;
      wmc[g] = ld_h8(ws + P_MC + off);
      float4 v = *(const float4*)(bb + g * 32 + q * 16 + 4 * c);
      acc_i[g][0] = v.x; acc_i[g][1] = v.y; acc_i[g][2] = v.z; acc_i[g][3] = v.w;
    }
    // fold spatial (time-invariant)
#pragma unroll
    for (int kt = 0; kt < 2; ++kt) {
      const float* sp = spatial + (size_t)seq * 64 + kt * 32 + c * 8;
      float4 a0 = *(const float4*)sp;
      float4 a1 = *(const float4*)(sp + 4);
      half8 sf = mk_h8(pk_f16(a0.x, a0.y), pk_f16(a0.z, a0.w),
                       pk_f16(a1.x, a1.y), pk_f16(a1.z, a1.w));
#pragma unroll
      for (int g = 0; g < 3; ++g) {
        int row = g * 32 + q * 16 + l15;
        half8 wsp = ld_h8(ws + P_SP + row * 64 + kt * 32 + c * 8);
        acc_i[g] = mfma_h(wsp, sf, acc_i[g]);
      }
    }
    const float* lptr = ((c < 2) ? met : ctx) + (size_t)seq * 16 + (c & 1) * 8;
    // xacc(0) -> buffer 0
    {
      float4 a0 = *(const float4*)lptr;
      float4 a1 = *(const float4*)(lptr + 4);
      half8 xf = mk_h8(pk_f16(a0.x, a0.y), pk_f16(a0.z, a0.w),
                       pk_f16(a1.x, a1.y), pk_f16(a1.z, a1.w));
#pragma unroll
      for (int g = 0; g < 3; ++g) {
        f32x4 D = mfma_h(wmc[g], xf, acc_i[g]);
        *(f32x4*)&xls[0][g * 2 + q][l15][c * 4] = D;
      }
    }
    // parity slots: slot s holds x(t+1) for step t with t&1==s
    float4 xs0a = *(const float4*)(lptr + (size_t)1 * NSEQ * 16);
    float4 xs0b = *(const float4*)(lptr + (size_t)1 * NSEQ * 16 + 4);
    float4 xs1a = *(const float4*)(lptr + (size_t)2 * NSEQ * 16);
    float4 xs1b = *(const float4*)(lptr + (size_t)2 * NSEQ * 16 + 4);

    barrier_lds();

#pragma unroll 2
    for (int t = 0; t < TSTEPS; ++t) {
      float4 xa = (t & 1) ? xs1a : xs0a;
      float4 xb = (t & 1) ? xs1b : xs0b;
      half8 xf = mk_h8(pk_f16(xa.x, xa.y), pk_f16(xa.z, xa.w),
                       pk_f16(xb.x, xb.y), pk_f16(xb.z, xb.w));
      // refill slot with x(t+3) (used at step t+2)
      {
        int tf = (t + 3 < TSTEPS) ? (t + 3) : (TSTEPS - 1);
        float4 na = *(const float4*)(lptr + (size_t)tf * NSEQ * 16);
        float4 nb = *(const float4*)(lptr + (size_t)tf * NSEQ * 16 + 4);
        if (t & 1) { xs1a = na; xs1b = nb; } else { xs0a = na; xs0b = nb; }
      }
      const int buf = (t + 1) & 1;
#pragma unroll
      for (int g = 0; g < 3; ++g) {
        f32x4 D = mfma_h(wmc[g], xf, acc_i[g]);
        *(f32x4*)&xls[buf][g * 2 + q][l15][c * 4] = D;
      }
      barrier_lds();
    }
    // producers done
  } else {
    // ======================= CONSUMER =======================
    const int p = wv;                // unit-half
    __builtin_amdgcn_s_setprio(1);   // favor the serial-path waves (T5)
    half8 whh[3];
#pragma unroll
    for (int g = 0; g < 3; ++g) {
      int off = (g * 32 + p * 16 + l15) * 32 + c * 8;
      whh[g] = ld_h8(ws + P_HH + off);
    }
    f32x4 bhn4;
    {
      float4 v = *(const float4*)(bb + 96 + p * 16 + 4 * c);
      bhn4[0] = v.x; bhn4[1] = v.y; bhn4[2] = v.z; bhn4[3] = v.w;
    }
    float hst[4] = {0.f, 0.f, 0.f, 0.f};
    unsigned int own0 = 0u, own1 = 0u;

    barrier_lds();

#pragma unroll 2
    for (int t = 0; t < TSTEPS; ++t) {
      // partner h' + xacc C-tiles (all LDS reads issued up front)
      const unsigned int* hp = &hbuf[(t + 1) & 1][1 - p][lane][0];
      unsigned int phx = hp[0], phy = hp[1];
      f32x4 xr = *(const f32x4*)&xls[t & 1][p][l15][c * 4];
      f32x4 xz = *(const f32x4*)&xls[t & 1][2 + p][l15][c * 4];
      f32x4 ti = *(const f32x4*)&xls[t & 1][4 + p][l15][c * 4];

      half8 fh = p ? mk_h8(phx, phy, own0, own1)
                   : mk_h8(own0, own1, phx, phy);

      f32x4 d0 = mfma_h(whh[0], fh, xr);    // r pre-act
      f32x4 d1 = mfma_h(whh[1], fh, xz);    // z pre-act
      f32x4 dn = mfma_h(whh[2], fh, bhn4);  // gh_n + b_hn

      // merged-rcp gates: h' = [h(1+e) + E(1-e)] / [(1+E)(1+e)]
      float hv_[4];
#pragma unroll
      for (int qq = 0; qq < 4; ++qq) {
        float R = exp2_fast(-d0[qq]);
        float r = __builtin_amdgcn_rcpf(1.0f + R);
        float E = fminf(exp2_fast(-d1[qq]), 1e30f);
        float Y = fmaf(r, dn[qq], ti[qq]);
        float e = fminf(exp2_fast(-Y), 1e30f);
        float oe = 1.0f + e, oE = 1.0f + E;
        float inv = __builtin_amdgcn_rcpf(oE * oe);
        float num = fmaf(hst[qq], oe, fmaf(-E, e, E));
        float hv = num * inv;
        hst[qq] = hv;
        hv_[qq] = hv;
      }
      own0 = pk_f16(hv_[0], hv_[1]);
      own1 = pk_f16(hv_[2], hv_[3]);
      hbuf[t & 1][p][lane][0] = own0;
      hbuf[t & 1][p][lane][1] = own1;

      barrier_lds();
    }

    // final h fragment (t=23 wrote hbuf[1], barrier done)
    half8 fh;
    {
      const unsigned int* hp = &hbuf[1][1 - p][lane][0];
      unsigned int phx = hp[0], phy = hp[1];
      fh = p ? mk_h8(phx, phy, own0, own1)
             : mk_h8(own0, own1, phx, phy);
    }
    // projection: wave p does f-tiles {p, 2+p}, f16 2-term
#pragma unroll
    for (int pt = 0; pt < 2; ++pt) {
      int ftile = pt * 2 + p;
      int off = (ftile * 16 + l15) * 32 + c * 8;
      half8 wph = ld_h8(ws + P_WP_H + off);
      half8 wpl = ld_h8(ws + P_WP_L + off);
      f32x4 o = mfma_h(wph, fh, zero4);
      o = mfma_h(wpl, fh, o);
      float* op = out + (size_t)seq * 64 + ftile * 16 + 4 * c;
      *(float4*)op = make_float4(o[0], o[1], o[2], o[3]);
    }
    __builtin_amdgcn_s_setprio(0);
  }
}

extern "C" void kernel_launch(void* const* d_in, const int* in_sizes, int n_in,
                              void* d_out, int out_size, void* d_ws, size_t ws_size,
                              hipStream_t stream) {
  const float* spatial = (const float*)d_in[0];
  const float* met     = (const float*)d_in[1];
  const float* ctx     = (const float*)d_in[2];
  const float* W_ih    = (const float*)d_in[3];
  const float* W_hh    = (const float*)d_in[4];
  const float* b_ih    = (const float*)d_in[5];
  const float* b_hh    = (const float*)d_in[6];
  const float* Wp      = (const float*)d_in[7];
  float* out = (float*)d_out;
  unsigned short* ws = (unsigned short*)d_ws;

  hipLaunchKernelGGL(pack_w, dim3(57), dim3(256), 0, stream,
                     W_ih, W_hh, b_ih, b_hh, Wp, ws);
  hipLaunchKernelGGL(gru7, dim3(1024), dim3(256), 0, stream,
                     spatial, met, ctx, ws, out);
}

// Round 12
// 25.159 us; speedup vs baseline: 1.2519x; 1.0434x over previous
//
#include <hip/hip_runtime.h>
#include <hip/hip_fp16.h>
#include <math.h>

// T=24, NSEQ=16384, FS=64, FM=16, FC=16 -> I=96; H=32.
//
// R12 = R11 (producer/consumer, 4 waves/block, 16 seqs/block, 1024 blocks)
// with pack_w ELIMINATED: every block gathers its own weight fragments
// directly from W_hh/W_ih/b_*/Wp in the prologue (sigma-layout columns
// {4c..4c+3, 16+4c..16+4c+3} = two contiguous float4 loads per row).
// Removes one graph node + inter-kernel gap + all d_ws traffic.
// Everything else identical to R11: consumers (waves 0,1) run the serial
// recurrence (3 f16 h-MFMAs + merged-rcp gates + uint2 h-exchange);
// producers (waves 2,3) compute xacc(t+1) into double-buffered LDS;
// one lgkm-only barrier per step; setprio(1) on consumers.

typedef __attribute__((ext_vector_type(8))) short short8;
typedef __attribute__((ext_vector_type(8))) _Float16 half8;
typedef __attribute__((ext_vector_type(4))) float f32x4;
typedef __attribute__((ext_vector_type(4))) unsigned int uix4;

#define NSEQ 16384
#define TSTEPS 24
#define LOG2E 1.44269504088896340736f

__device__ __forceinline__ float exp2_fast(float x) {
#if __has_builtin(__builtin_amdgcn_exp2f)
  return __builtin_amdgcn_exp2f(x);
#else
  return __expf(x * 0.6931471805599453f);
#endif
}

// runtime pack (round-toward-zero, fast) — used for x/h/spatial data
__device__ __forceinline__ unsigned int pk_f16(float a, float b) {
#if __has_builtin(__builtin_amdgcn_cvt_pkrtz)
  auto r = __builtin_amdgcn_cvt_pkrtz(a, b);   // __fp16 ext_vector(2)
  return __builtin_bit_cast(unsigned int, r);
#else
  return (unsigned)__half_as_ushort(__float2half(a)) |
         ((unsigned)__half_as_ushort(__float2half(b)) << 16);
#endif
}

// prologue pack (round-nearest, matches old pack_w numerics) — weights
__device__ __forceinline__ unsigned int pk_f16_rn(float a, float b) {
  return (unsigned)__half_as_ushort(__float2half(a)) |
         ((unsigned)__half_as_ushort(__float2half(b)) << 16);
}

__device__ __forceinline__ half8 mk_h8(unsigned int a, unsigned int b,
                                       unsigned int c, unsigned int d) {
  uix4 v = {a, b, c, d};
  return __builtin_bit_cast(half8, v);
}

__device__ __forceinline__ f32x4 mfma_h(half8 a, half8 b, f32x4 c) {
  return __builtin_amdgcn_mfma_f32_16x16x32_f16(a, b, c, 0, 0, 0);
}

// workgroup barrier draining LDS ops only — global prefetch stays in flight
__device__ __forceinline__ void barrier_lds() {
  asm volatile("s_waitcnt lgkmcnt(0)" ::: "memory");
  __builtin_amdgcn_s_barrier();
}

__global__ __launch_bounds__(256, 4)
void gru8(const float* __restrict__ spatial,
          const float* __restrict__ met,
          const float* __restrict__ ctx,
          const float* __restrict__ W_ih,
          const float* __restrict__ W_hh,
          const float* __restrict__ b_ih,
          const float* __restrict__ b_hh,
          const float* __restrict__ Wp,
          float* __restrict__ out) {
  // xacc tiles: [buf][tile(gate*2+half)][seq 16][20-pad f32]
  __shared__ float xls[2][6][16][20];
  __shared__ unsigned int hbuf[2][2][64][2];

  const int tid = threadIdx.x;
  const int lane = tid & 63;
  const int wv = tid >> 6;       // 0,1 consumer; 2,3 producer
  const int l15 = lane & 15;
  const int c = lane >> 4;       // 0..3
  const int seq = blockIdx.x * 16 + l15;
  const f32x4 zero4 = {0.f, 0.f, 0.f, 0.f};

  // zero initial-h buffer (hbuf[1] = 256 dwords; one per thread)
  ((unsigned int*)hbuf[1])[tid] = 0u;

  if (wv >= 2) {
    // ======================= PRODUCER =======================
    const int q = wv - 2;            // unit-half
    half8 wmc[3];
    f32x4 acc_i[3];
#pragma unroll
    for (int g = 0; g < 3; ++g) {
      const float sc = (g < 2) ? LOG2E : (2.0f * LOG2E);
      const int rowb = g * 32 + q * 16;
      // W_ih met|ctx columns 64 + c*8 .. +7 (natural k)
      const float* wrow = W_ih + (size_t)(rowb + l15) * 96 + 64 + c * 8;
      float4 wa = *(const float4*)wrow;
      float4 wb = *(const float4*)(wrow + 4);
      wmc[g] = mk_h8(pk_f16_rn(wa.x * sc, wa.y * sc),
                     pk_f16_rn(wa.z * sc, wa.w * sc),
                     pk_f16_rn(wb.x * sc, wb.y * sc),
                     pk_f16_rn(wb.z * sc, wb.w * sc));
      // bias: (b_ih + b_hh for r,z) * sc
      float4 vih = *(const float4*)(b_ih + rowb + 4 * c);
      if (g < 2) {
        float4 vhh = *(const float4*)(b_hh + rowb + 4 * c);
        acc_i[g][0] = (vih.x + vhh.x) * sc; acc_i[g][1] = (vih.y + vhh.y) * sc;
        acc_i[g][2] = (vih.z + vhh.z) * sc; acc_i[g][3] = (vih.w + vhh.w) * sc;
      } else {
        acc_i[g][0] = vih.x * sc; acc_i[g][1] = vih.y * sc;
        acc_i[g][2] = vih.z * sc; acc_i[g][3] = vih.w * sc;
      }
    }
    // fold spatial (time-invariant): W_ih cols kt*32 + c*8 .. +7
#pragma unroll
    for (int kt = 0; kt < 2; ++kt) {
      const float* sp = spatial + (size_t)seq * 64 + kt * 32 + c * 8;
      float4 a0 = *(const float4*)sp;
      float4 a1 = *(const float4*)(sp + 4);
      half8 sf = mk_h8(pk_f16(a0.x, a0.y), pk_f16(a0.z, a0.w),
                       pk_f16(a1.x, a1.y), pk_f16(a1.z, a1.w));
#pragma unroll
      for (int g = 0; g < 3; ++g) {
        const float sc = (g < 2) ? LOG2E : (2.0f * LOG2E);
        const float* wrow = W_ih + (size_t)(g * 32 + q * 16 + l15) * 96 +
                            kt * 32 + c * 8;
        float4 wa = *(const float4*)wrow;
        float4 wb = *(const float4*)(wrow + 4);
        half8 wsp = mk_h8(pk_f16_rn(wa.x * sc, wa.y * sc),
                          pk_f16_rn(wa.z * sc, wa.w * sc),
                          pk_f16_rn(wb.x * sc, wb.y * sc),
                          pk_f16_rn(wb.z * sc, wb.w * sc));
        acc_i[g] = mfma_h(wsp, sf, acc_i[g]);
      }
    }
    const float* lptr = ((c < 2) ? met : ctx) + (size_t)seq * 16 + (c & 1) * 8;
    // xacc(0) -> buffer 0
    {
      float4 a0 = *(const float4*)lptr;
      float4 a1 = *(const float4*)(lptr + 4);
      half8 xf = mk_h8(pk_f16(a0.x, a0.y), pk_f16(a0.z, a0.w),
                       pk_f16(a1.x, a1.y), pk_f16(a1.z, a1.w));
#pragma unroll
      for (int g = 0; g < 3; ++g) {
        f32x4 D = mfma_h(wmc[g], xf, acc_i[g]);
        *(f32x4*)&xls[0][g * 2 + q][l15][c * 4] = D;
      }
    }
    // parity slots: slot s holds x(t+1) for step t with t&1==s
    float4 xs0a = *(const float4*)(lptr + (size_t)1 * NSEQ * 16);
    float4 xs0b = *(const float4*)(lptr + (size_t)1 * NSEQ * 16 + 4);
    float4 xs1a = *(const float4*)(lptr + (size_t)2 * NSEQ * 16);
    float4 xs1b = *(const float4*)(lptr + (size_t)2 * NSEQ * 16 + 4);

    barrier_lds();

#pragma unroll 2
    for (int t = 0; t < TSTEPS; ++t) {
      float4 xa = (t & 1) ? xs1a : xs0a;
      float4 xb = (t & 1) ? xs1b : xs0b;
      half8 xf = mk_h8(pk_f16(xa.x, xa.y), pk_f16(xa.z, xa.w),
                       pk_f16(xb.x, xb.y), pk_f16(xb.z, xb.w));
      // refill slot with x(t+3) (used at step t+2)
      {
        int tf = (t + 3 < TSTEPS) ? (t + 3) : (TSTEPS - 1);
        float4 na = *(const float4*)(lptr + (size_t)tf * NSEQ * 16);
        float4 nb = *(const float4*)(lptr + (size_t)tf * NSEQ * 16 + 4);
        if (t & 1) { xs1a = na; xs1b = nb; } else { xs0a = na; xs0b = nb; }
      }
      const int buf = (t + 1) & 1;
#pragma unroll
      for (int g = 0; g < 3; ++g) {
        f32x4 D = mfma_h(wmc[g], xf, acc_i[g]);
        *(f32x4*)&xls[buf][g * 2 + q][l15][c * 4] = D;
      }
      barrier_lds();
    }
    // producers done
  } else {
    // ======================= CONSUMER =======================
    const int p = wv;                // unit-half
    __builtin_amdgcn_s_setprio(1);   // favor the serial-path waves (T5)
    // W_hh sigma-layout fragment: cols {4c..4c+3, 16+4c..16+4c+3}
    half8 whh[3];
#pragma unroll
    for (int g = 0; g < 3; ++g) {
      const float sc = (g < 2) ? LOG2E : (2.0f * LOG2E);
      const float* wrow = W_hh + (size_t)(g * 32 + p * 16 + l15) * 32;
      float4 a = *(const float4*)(wrow + 4 * c);
      float4 b = *(const float4*)(wrow + 16 + 4 * c);
      whh[g] = mk_h8(pk_f16_rn(a.x * sc, a.y * sc),
                     pk_f16_rn(a.z * sc, a.w * sc),
                     pk_f16_rn(b.x * sc, b.y * sc),
                     pk_f16_rn(b.z * sc, b.w * sc));
    }
    f32x4 bhn4;
    {
      float4 v = *(const float4*)(b_hh + 64 + p * 16 + 4 * c);
      bhn4[0] = 2.0f * LOG2E * v.x; bhn4[1] = 2.0f * LOG2E * v.y;
      bhn4[2] = 2.0f * LOG2E * v.z; bhn4[3] = 2.0f * LOG2E * v.w;
    }
    float hst[4] = {0.f, 0.f, 0.f, 0.f};
    unsigned int own0 = 0u, own1 = 0u;

    barrier_lds();

#pragma unroll 2
    for (int t = 0; t < TSTEPS; ++t) {
      // partner h' + xacc C-tiles (all LDS reads issued up front)
      const unsigned int* hp = &hbuf[(t + 1) & 1][1 - p][lane][0];
      unsigned int phx = hp[0], phy = hp[1];
      f32x4 xr = *(const f32x4*)&xls[t & 1][p][l15][c * 4];
      f32x4 xz = *(const f32x4*)&xls[t & 1][2 + p][l15][c * 4];
      f32x4 ti = *(const f32x4*)&xls[t & 1][4 + p][l15][c * 4];

      half8 fh = p ? mk_h8(phx, phy, own0, own1)
                   : mk_h8(own0, own1, phx, phy);

      f32x4 d0 = mfma_h(whh[0], fh, xr);    // r pre-act
      f32x4 d1 = mfma_h(whh[1], fh, xz);    // z pre-act
      f32x4 dn = mfma_h(whh[2], fh, bhn4);  // gh_n + b_hn

      // merged-rcp gates: h' = [h(1+e) + E(1-e)] / [(1+E)(1+e)]
      float hv_[4];
#pragma unroll
      for (int qq = 0; qq < 4; ++qq) {
        float R = exp2_fast(-d0[qq]);
        float r = __builtin_amdgcn_rcpf(1.0f + R);
        float E = fminf(exp2_fast(-d1[qq]), 1e30f);
        float Y = fmaf(r, dn[qq], ti[qq]);
        float e = fminf(exp2_fast(-Y), 1e30f);
        float oe = 1.0f + e, oE = 1.0f + E;
        float inv = __builtin_amdgcn_rcpf(oE * oe);
        float num = fmaf(hst[qq], oe, fmaf(-E, e, E));
        float hv = num * inv;
        hst[qq] = hv;
        hv_[qq] = hv;
      }
      own0 = pk_f16(hv_[0], hv_[1]);
      own1 = pk_f16(hv_[2], hv_[3]);
      hbuf[t & 1][p][lane][0] = own0;
      hbuf[t & 1][p][lane][1] = own1;

      barrier_lds();
    }

    // final h fragment (t=23 wrote hbuf[1], barrier done)
    half8 fh;
    {
      const unsigned int* hp = &hbuf[1][1 - p][lane][0];
      unsigned int phx = hp[0], phy = hp[1];
      fh = p ? mk_h8(phx, phy, own0, own1)
             : mk_h8(own0, own1, phx, phy);
    }
    // projection: wave p does f-tiles {p, 2+p}; Wp gathered directly
    // (sigma cols: e<4 -> 4c+e, else 16+4c+e-4; stride-64 scattered)
#pragma unroll
    for (int pt = 0; pt < 2; ++pt) {
      int ftile = pt * 2 + p;
      int frow = ftile * 16 + l15;
      const float* wpb = Wp + frow;
      float v[8];
#pragma unroll
      for (int e = 0; e < 8; ++e) {
        int col = (e < 4) ? (4 * c + e) : (16 + 4 * c + (e - 4));
        v[e] = wpb[(size_t)col * 64];
      }
      unsigned int uh[4], ul[4];
#pragma unroll
      for (int e2 = 0; e2 < 4; ++e2) {
        float va = v[2 * e2], vb = v[2 * e2 + 1];
        __half ha = __float2half(va), hb = __float2half(vb);
        float la = va - __half2float(ha), lb = vb - __half2float(hb);
        uh[e2] = (unsigned)__half_as_ushort(ha) |
                 ((unsigned)__half_as_ushort(hb) << 16);
        ul[e2] = pk_f16_rn(la, lb);
      }
      half8 wph = mk_h8(uh[0], uh[1], uh[2], uh[3]);
      half8 wpl = mk_h8(ul[0], ul[1], ul[2], ul[3]);
      f32x4 o = mfma_h(wph, fh, zero4);
      o = mfma_h(wpl, fh, o);
      float* op = out + (size_t)seq * 64 + ftile * 16 + 4 * c;
      *(float4*)op = make_float4(o[0], o[1], o[2], o[3]);
    }
    __builtin_amdgcn_s_setprio(0);
  }
}

extern "C" void kernel_launch(void* const* d_in, const int* in_sizes, int n_in,
                              void* d_out, int out_size, void* d_ws, size_t ws_size,
                              hipStream_t stream) {
  const float* spatial = (const float*)d_in[0];
  const float* met     = (const float*)d_in[1];
  const float* ctx     = (const float*)d_in[2];
  const float* W_ih    = (const float*)d_in[3];
  const float* W_hh    = (const float*)d_in[4];
  const float* b_ih    = (const float*)d_in[5];
  const float* b_hh    = (const float*)d_in[6];
  const float* Wp      = (const float*)d_in[7];
  float* out = (float*)d_out;

  hipLaunchKernelGGL(gru8, dim3(1024), dim3(256), 0, stream,
                     spatial, met, ctx, W_ih, W_hh, b_ih, b_hh, Wp, out);
}